// Round 1
// baseline (91.401 us; speedup 1.0000x reference)
//
#include <hip/hip_runtime.h>
#include <stdint.h>

// LUTLayer forward, MI355X.
// x: (2048, 4096) f32 in {0,1}; mapping: (4096, 6) i32; luts: (4096, 64) f32.
// out[b][j] = (luts[j][ sum_k x[b][mapping[j][k]] << k ] > 0) ? 1.0f : 0.0f
//
// Strategy:
//  1) pack_x: xbits[g][m] (uint32) bit r = (x[g*32+r][m] != 0); g in [0,64), m in [0,4096).
//     Transposed packing => 6 word gathers give address bits for 32 batch rows at once.
//  2) lut_sign: lut_pos[j] = 64-bit mask of (luts[j][e] > 0) via wave ballot.
//  3) lut_fwd: block = (group g, col-block of 512 cols); 16 KB LDS bit image;
//     per thread: 2 cols, 12 LDS gathers, then 32 rows x 2 cols of pure VALU + float2 store.

static constexpr int IN   = 4096;
static constexpr int OUTW = 4096;
static constexpr int BATCH = 2048;

__global__ __launch_bounds__(256) void pack_x_kernel(const float* __restrict__ x,
                                                     uint32_t* __restrict__ xbits) {
    const int g = blockIdx.x >> 2;          // 64 row-groups of 32
    const int chunk = blockIdx.x & 3;       // 4 chunks of 1024 positions
    const int m = chunk * 1024 + threadIdx.x * 4;
    const float* xb = x + ((size_t)g * 32) * IN + m;
    uint32_t v0 = 0, v1 = 0, v2 = 0, v3 = 0;
#pragma unroll
    for (int r = 0; r < 32; ++r) {
        const float4 f = *(const float4*)(xb + (size_t)r * IN);
        v0 |= ((uint32_t)(f.x != 0.0f)) << r;
        v1 |= ((uint32_t)(f.y != 0.0f)) << r;
        v2 |= ((uint32_t)(f.z != 0.0f)) << r;
        v3 |= ((uint32_t)(f.w != 0.0f)) << r;
    }
    *(uint4*)(xbits + (size_t)g * IN + m) = make_uint4(v0, v1, v2, v3);
}

__global__ __launch_bounds__(256) void lut_sign_kernel(const float* __restrict__ luts,
                                                       unsigned long long* __restrict__ lut_pos) {
    const int wave = threadIdx.x >> 6;
    const int lane = threadIdx.x & 63;
    const int j = blockIdx.x * 4 + wave;    // 4096 rows / 4 waves per block
    const float v = luts[j * 64 + lane];
    const unsigned long long msk = __ballot(v > 0.0f);
    if (lane == 0) lut_pos[j] = msk;
}

__global__ __launch_bounds__(256) void lut_fwd_kernel(const int* __restrict__ mapping,
                                                      const uint32_t* __restrict__ xbits,
                                                      const unsigned long long* __restrict__ lut_pos,
                                                      float* __restrict__ out) {
    __shared__ uint32_t sbits[IN];          // 16 KB bit image for this row-group
    const int g  = blockIdx.x & 63;         // row-group
    const int cb = blockIdx.x >> 6;         // col-block (0..7), 512 cols each
    {
        const uint4* src = (const uint4*)(xbits + (size_t)g * IN);
        uint4* dst = (uint4*)sbits;
#pragma unroll
        for (int i = 0; i < 4; ++i) dst[threadIdx.x + i * 256] = src[threadIdx.x + i * 256];
    }
    __syncthreads();

    const int j = cb * 512 + threadIdx.x * 2;            // this thread: cols j, j+1
    const int4* mrow = (const int4*)(mapping + (size_t)j * 6);  // 12 ints, 16B-aligned (j even)
    const int4 q0 = mrow[0];   // c0: k0..k3
    const int4 q1 = mrow[1];   // c0: k4,k5 ; c1: k0,k1
    const int4 q2 = mrow[2];   // c1: k2..k5

    const uint32_t w00 = sbits[q0.x], w01 = sbits[q0.y], w02 = sbits[q0.z],
                   w03 = sbits[q0.w], w04 = sbits[q1.x], w05 = sbits[q1.y];
    const uint32_t w10 = sbits[q1.z], w11 = sbits[q1.w], w12 = sbits[q2.x],
                   w13 = sbits[q2.y], w14 = sbits[q2.z], w15 = sbits[q2.w];
    const ulonglong2 masks = *(const ulonglong2*)(lut_pos + j);

    float* outp = out + ((size_t)g * 32) * OUTW + j;
#pragma unroll
    for (int r = 0; r < 32; ++r) {
        const uint32_t a0 = ((w00 >> r) & 1u)        | (((w01 >> r) & 1u) << 1)
                          | (((w02 >> r) & 1u) << 2) | (((w03 >> r) & 1u) << 3)
                          | (((w04 >> r) & 1u) << 4) | (((w05 >> r) & 1u) << 5);
        const uint32_t a1 = ((w10 >> r) & 1u)        | (((w11 >> r) & 1u) << 1)
                          | (((w12 >> r) & 1u) << 2) | (((w13 >> r) & 1u) << 3)
                          | (((w14 >> r) & 1u) << 4) | (((w15 >> r) & 1u) << 5);
        float2 res;
        res.x = (float)((uint32_t)(masks.x >> a0) & 1u);
        res.y = (float)((uint32_t)(masks.y >> a1) & 1u);
        *(float2*)(outp + (size_t)r * OUTW) = res;
    }
}

// Fallback if workspace is too small: direct per-output computation.
__global__ __launch_bounds__(256) void naive_kernel(const float* __restrict__ x,
                                                    const int* __restrict__ mapping,
                                                    const float* __restrict__ luts,
                                                    float* __restrict__ out) {
    const int idx = blockIdx.x * 256 + threadIdx.x;
    const int b = idx >> 12;                 // / 4096
    const int j = idx & (OUTW - 1);
    const float* xr = x + (size_t)b * IN;
    int addr = 0;
#pragma unroll
    for (int k = 0; k < 6; ++k) {
        addr |= ((int)(xr[mapping[j * 6 + k]] != 0.0f)) << k;
    }
    out[idx] = (luts[j * 64 + addr] > 0.0f) ? 1.0f : 0.0f;
}

extern "C" void kernel_launch(void* const* d_in, const int* in_sizes, int n_in,
                              void* d_out, int out_size, void* d_ws, size_t ws_size,
                              hipStream_t stream) {
    const float* x       = (const float*)d_in[0];
    const int*   mapping = (const int*)d_in[1];
    const float* luts    = (const float*)d_in[2];
    float* out = (float*)d_out;

    const size_t lut_pos_bytes = (size_t)OUTW * 8;            // 32 KB
    const size_t xbits_bytes   = (size_t)64 * IN * 4;         // 1 MB
    if (ws_size >= lut_pos_bytes + xbits_bytes) {
        unsigned long long* lut_pos = (unsigned long long*)d_ws;
        uint32_t* xbits = (uint32_t*)((char*)d_ws + lut_pos_bytes);
        hipLaunchKernelGGL(pack_x_kernel, dim3(256), dim3(256), 0, stream, x, xbits);
        hipLaunchKernelGGL(lut_sign_kernel, dim3(1024), dim3(256), 0, stream, luts, lut_pos);
        hipLaunchKernelGGL(lut_fwd_kernel, dim3(512), dim3(256), 0, stream,
                           mapping, xbits, lut_pos, out);
    } else {
        hipLaunchKernelGGL(naive_kernel, dim3((BATCH * OUTW) / 256), dim3(256), 0, stream,
                           x, mapping, luts, out);
    }
}

// Round 2
// 91.384 us; speedup vs baseline: 1.0002x; 1.0002x over previous
//
#include <hip/hip_runtime.h>
#include <stdint.h>

// LUTLayer forward, MI355X (gfx950).
// x: (2048, 4096) f32 in {0,1}; mapping: (4096, 6) i32; luts: (4096, 64) f32.
// out[b][j] = (luts[j][ sum_k x[b][mapping[j][k]] << k ] > 0) ? 1.0f : 0.0f
//
// R1 result: 91.4 us, absmax 0. Profile shows harness reset fills (268 MB d_ws
// poison @44us) dominating the timed window; our 3 kernels sum ~14-15 us vs
// ~11 us HBM floor. R2: fuse pack_x + lut_sign into one dispatch (saves a
// launch gap, overlaps the tiny sign pass), pipeline the ballot loop 4-wide.
//
// Structure:
//  Kernel A (288 blocks):
//    blocks [0,256): pack xbits[g][m] (uint32), bit r = (x[g*32+r][m] != 0).
//      Transposed bit-pack => 6 word gathers give addresses for 32 rows at once.
//    blocks [256,288): lut_pos[j] = 64-bit ballot mask of (luts[j][e] > 0).
//      (clip to [-1,1] preserves sign; only sign matters for the output.)
//  Kernel B (512 blocks): block = (row-group g, 512-col block); 16 KB LDS bit
//    image; 12 LDS gathers/thread, then 32 rows x 2 cols pure VALU + float2 store.

static constexpr int IN    = 4096;
static constexpr int OUTW  = 4096;
static constexpr int BATCH = 2048;

__global__ __launch_bounds__(256) void prep_kernel(const float* __restrict__ x,
                                                   const float* __restrict__ luts,
                                                   uint32_t* __restrict__ xbits,
                                                   unsigned long long* __restrict__ lut_pos) {
    if (blockIdx.x < 256) {
        // ---- bit-pack x (transposed): 64 row-groups x 4 col-chunks ----
        const int g = blockIdx.x >> 2;
        const int chunk = blockIdx.x & 3;
        const int m = chunk * 1024 + threadIdx.x * 4;
        const float* xb = x + ((size_t)g * 32) * IN + m;
        uint32_t v0 = 0, v1 = 0, v2 = 0, v3 = 0;
#pragma unroll
        for (int r = 0; r < 32; ++r) {
            const float4 f = *(const float4*)(xb + (size_t)r * IN);
            v0 |= ((uint32_t)(f.x != 0.0f)) << r;
            v1 |= ((uint32_t)(f.y != 0.0f)) << r;
            v2 |= ((uint32_t)(f.z != 0.0f)) << r;
            v3 |= ((uint32_t)(f.w != 0.0f)) << r;
        }
        *(uint4*)(xbits + (size_t)g * IN + m) = make_uint4(v0, v1, v2, v3);
    } else {
        // ---- lut sign masks: 32 blocks x 4 waves x 32 rows, 4-wide pipelined ----
        const int wave = threadIdx.x >> 6;
        const int lane = threadIdx.x & 63;
        const int base = (blockIdx.x - 256) * 128 + wave * 32;
#pragma unroll
        for (int i = 0; i < 32; i += 4) {
            const float v0 = luts[(size_t)(base + i + 0) * 64 + lane];
            const float v1 = luts[(size_t)(base + i + 1) * 64 + lane];
            const float v2 = luts[(size_t)(base + i + 2) * 64 + lane];
            const float v3 = luts[(size_t)(base + i + 3) * 64 + lane];
            const unsigned long long m0 = __ballot(v0 > 0.0f);
            const unsigned long long m1 = __ballot(v1 > 0.0f);
            const unsigned long long m2 = __ballot(v2 > 0.0f);
            const unsigned long long m3 = __ballot(v3 > 0.0f);
            if (lane == 0) {
                lut_pos[base + i + 0] = m0;
                lut_pos[base + i + 1] = m1;
                lut_pos[base + i + 2] = m2;
                lut_pos[base + i + 3] = m3;
            }
        }
    }
}

__global__ __launch_bounds__(256) void lut_fwd_kernel(const int* __restrict__ mapping,
                                                      const uint32_t* __restrict__ xbits,
                                                      const unsigned long long* __restrict__ lut_pos,
                                                      float* __restrict__ out) {
    __shared__ uint32_t sbits[IN];          // 16 KB bit image for this row-group
    const int g  = blockIdx.x & 63;         // row-group
    const int cb = blockIdx.x >> 6;         // col-block (0..7), 512 cols each
    {
        const uint4* src = (const uint4*)(xbits + (size_t)g * IN);
        uint4* dst = (uint4*)sbits;
#pragma unroll
        for (int i = 0; i < 4; ++i) dst[threadIdx.x + i * 256] = src[threadIdx.x + i * 256];
    }
    __syncthreads();

    const int j = cb * 512 + threadIdx.x * 2;            // this thread: cols j, j+1
    const int4* mrow = (const int4*)(mapping + (size_t)j * 6);  // 12 ints, 16B-aligned
    const int4 q0 = mrow[0];   // c0: k0..k3
    const int4 q1 = mrow[1];   // c0: k4,k5 ; c1: k0,k1
    const int4 q2 = mrow[2];   // c1: k2..k5

    const uint32_t w00 = sbits[q0.x], w01 = sbits[q0.y], w02 = sbits[q0.z],
                   w03 = sbits[q0.w], w04 = sbits[q1.x], w05 = sbits[q1.y];
    const uint32_t w10 = sbits[q1.z], w11 = sbits[q1.w], w12 = sbits[q2.x],
                   w13 = sbits[q2.y], w14 = sbits[q2.z], w15 = sbits[q2.w];
    const ulonglong2 masks = *(const ulonglong2*)(lut_pos + j);

    float* outp = out + ((size_t)g * 32) * OUTW + j;
#pragma unroll
    for (int r = 0; r < 32; ++r) {
        const uint32_t a0 = ((w00 >> r) & 1u)        | (((w01 >> r) & 1u) << 1)
                          | (((w02 >> r) & 1u) << 2) | (((w03 >> r) & 1u) << 3)
                          | (((w04 >> r) & 1u) << 4) | (((w05 >> r) & 1u) << 5);
        const uint32_t a1 = ((w10 >> r) & 1u)        | (((w11 >> r) & 1u) << 1)
                          | (((w12 >> r) & 1u) << 2) | (((w13 >> r) & 1u) << 3)
                          | (((w14 >> r) & 1u) << 4) | (((w15 >> r) & 1u) << 5);
        float2 res;
        res.x = (float)((uint32_t)(masks.x >> a0) & 1u);
        res.y = (float)((uint32_t)(masks.y >> a1) & 1u);
        *(float2*)(outp + (size_t)r * OUTW) = res;
    }
}

// Fallback if workspace is too small: direct per-output computation.
__global__ __launch_bounds__(256) void naive_kernel(const float* __restrict__ x,
                                                    const int* __restrict__ mapping,
                                                    const float* __restrict__ luts,
                                                    float* __restrict__ out) {
    const int idx = blockIdx.x * 256 + threadIdx.x;
    const int b = idx >> 12;
    const int j = idx & (OUTW - 1);
    const float* xr = x + (size_t)b * IN;
    int addr = 0;
#pragma unroll
    for (int k = 0; k < 6; ++k) {
        addr |= ((int)(xr[mapping[j * 6 + k]] != 0.0f)) << k;
    }
    out[idx] = (luts[j * 64 + addr] > 0.0f) ? 1.0f : 0.0f;
}

extern "C" void kernel_launch(void* const* d_in, const int* in_sizes, int n_in,
                              void* d_out, int out_size, void* d_ws, size_t ws_size,
                              hipStream_t stream) {
    const float* x       = (const float*)d_in[0];
    const int*   mapping = (const int*)d_in[1];
    const float* luts    = (const float*)d_in[2];
    float* out = (float*)d_out;

    const size_t lut_pos_bytes = (size_t)OUTW * 8;            // 32 KB
    const size_t xbits_bytes   = (size_t)64 * IN * 4;         // 1 MB
    if (ws_size >= lut_pos_bytes + xbits_bytes) {
        unsigned long long* lut_pos = (unsigned long long*)d_ws;
        uint32_t* xbits = (uint32_t*)((char*)d_ws + lut_pos_bytes);
        hipLaunchKernelGGL(prep_kernel, dim3(288), dim3(256), 0, stream,
                           x, luts, xbits, lut_pos);
        hipLaunchKernelGGL(lut_fwd_kernel, dim3(512), dim3(256), 0, stream,
                           mapping, xbits, lut_pos, out);
    } else {
        hipLaunchKernelGGL(naive_kernel, dim3((BATCH * OUTW) / 256), dim3(256), 0, stream,
                           x, mapping, luts, out);
    }
}